// Round 6
// baseline (406.859 us; speedup 1.0000x reference)
//
#include <hip/hip_runtime.h>
#include <stdint.h>

// ---------------- common helpers ----------------
typedef __attribute__((ext_vector_type(8))) short short8;
typedef __attribute__((ext_vector_type(4))) short short4v;
typedef __attribute__((ext_vector_type(4))) float float4v;
typedef __attribute__((ext_vector_type(8))) __bf16 bf16x8;

#define NCH 4  // attention S-dim split factor

__device__ __forceinline__ float4v mfma16x16x32(short8 a, short8 b, float4v c) {
  return __builtin_amdgcn_mfma_f32_16x16x32_bf16(
      __builtin_bit_cast(bf16x8, a), __builtin_bit_cast(bf16x8, b), c, 0, 0, 0);
}

// float -> bf16 (RNE), as raw short
__device__ __forceinline__ short f2bf(float f) {
  uint32_t u = __builtin_bit_cast(uint32_t, f);
  u += 0x7fffu + ((u >> 16) & 1u);
  return (short)(u >> 16);
}

__device__ __forceinline__ float bf2f(short s) {
  return __builtin_bit_cast(float, ((uint32_t)(uint16_t)s) << 16);
}

// async 16B global->LDS. LDS dst = wave-uniform base + lane*16 at all sites.
__device__ __forceinline__ void load_lds16(const short* g, short* l) {
  __builtin_amdgcn_global_load_lds(
      (const __attribute__((address_space(1))) void*)g,
      (__attribute__((address_space(3))) void*)l, 16, 0, 0);
}

// ---------------- fused fp32 -> bf16 for lang + 4 weights ----------------
__global__ __launch_bounds__(256) void convert5(
    const float* __restrict__ sl, short* __restrict__ dl,
    const float* __restrict__ s1, short* __restrict__ d1,
    const float* __restrict__ s2, short* __restrict__ d2,
    const float* __restrict__ s3, short* __restrict__ d3,
    const float* __restrict__ s4, short* __restrict__ d4) {
  const float* src; short* dst; int n4;
  switch (blockIdx.y) {
    case 0: src = sl; dst = dl; n4 = 131072; break;
    case 1: src = s1; dst = d1; n4 = 65536; break;
    case 2: src = s2; dst = d2; n4 = 65536; break;
    case 3: src = s3; dst = d3; n4 = 65536; break;
    default: src = s4; dst = d4; n4 = 65536; break;
  }
  const int stride = gridDim.x * blockDim.x;
  for (int i = blockIdx.x * blockDim.x + threadIdx.x; i < n4; i += stride) {
    float4v v = *(const float4v*)(src + (long)i * 4);
    short4v o;
#pragma unroll
    for (int r = 0; r < 4; r++) o[r] = f2bf(v[r]);
    *(short4v*)(dst + (long)i * 4) = o;
  }
}

// ---------------- small NT GEMM (q / out projections) ----------------
// C[m,n] = scale * sum_k A[m,k]*B[n,k]; 128x128 tile, BK=32, 4 waves.
// OUT_F32=1: C fp32; else bf16.
template <int OUT_F32>
__global__ __launch_bounds__(256) void gemm_nt(
    const short* __restrict__ A, const short* __restrict__ B,
    void* __restrict__ C, int K, int ldc, float scale) {
  __shared__ alignas(16) short lA[128 * 32];
  __shared__ alignas(16) short lB[128 * 32];
  const int tid = threadIdx.x;
  const int lane = tid & 63, w = tid >> 6;
  const int quad = lane >> 4, l16 = lane & 15;
  const int wm = w >> 1, wn = w & 1;
  const long m0 = (long)blockIdx.y * 128, n0 = (long)blockIdx.x * 128;

  float4v acc[4][4];
#pragma unroll
  for (int i = 0; i < 4; i++)
#pragma unroll
    for (int j = 0; j < 4; j++) acc[i][j] = (float4v)0.0f;

  const int srow = tid >> 2;
  const int scol = (tid & 3) * 8;

  for (int kt = 0; kt < K; kt += 32) {
    load_lds16(&A[(m0 + srow) * K + kt + scol], &lA[tid * 8]);
    load_lds16(&A[(m0 + 64 + srow) * K + kt + scol], &lA[2048 + tid * 8]);
    load_lds16(&B[(n0 + srow) * K + kt + scol], &lB[tid * 8]);
    load_lds16(&B[(n0 + 64 + srow) * K + kt + scol], &lB[2048 + tid * 8]);
    __syncthreads();

    short8 af[4], bf[4];
#pragma unroll
    for (int t = 0; t < 4; t++) {
      af[t] = *(const short8*)&lA[(wm * 64 + t * 16 + l16) * 32 + quad * 8];
      bf[t] = *(const short8*)&lB[(wn * 64 + t * 16 + l16) * 32 + quad * 8];
    }
#pragma unroll
    for (int i = 0; i < 4; i++)
#pragma unroll
      for (int j = 0; j < 4; j++)
        acc[i][j] = mfma16x16x32(af[i], bf[j], acc[i][j]);
    __syncthreads();
  }

  const int cm = wm * 64 + quad * 4;
  const int cn = wn * 64 + l16;
  if (OUT_F32) {
    float* Cf = (float*)C;
#pragma unroll
    for (int i = 0; i < 4; i++)
#pragma unroll
      for (int j = 0; j < 4; j++) {
        const long gn = n0 + cn + j * 16;
#pragma unroll
        for (int r = 0; r < 4; r++)
          Cf[(m0 + cm + i * 16 + r) * (long)ldc + gn] = acc[i][j][r] * scale;
      }
  } else {
    short* Cs = (short*)C;
#pragma unroll
    for (int i = 0; i < 4; i++)
#pragma unroll
      for (int j = 0; j < 4; j++) {
        const long gn = n0 + cn + j * 16;
#pragma unroll
        for (int r = 0; r < 4; r++)
          Cs[(m0 + cm + i * 16 + r) * (long)ldc + gn] = f2bf(acc[i][j][r] * scale);
      }
  }
}

// ---------------- fused KV projection ----------------
// k[s][i] (TRANS, coalesced via LDS retile) and v[i][s] from shared visT tile.
// 512 threads = 8 waves: w0..3 -> k (Wk), w4..7 -> v (Wv); each 4-wave set is
// a 2x2 wave grid over the 128i x 128s tile. grid=(S/128, I/128, Bg).
__global__ __launch_bounds__(512) void gemm_kv(
    const short* __restrict__ Wk, const short* __restrict__ Wv,
    const short* __restrict__ visT, long sV,
    short* __restrict__ kout, short* __restrict__ vout, long sKV) {
  __shared__ alignas(16) short smem[12288];  // lWk | lWv | lVis; scratch aliases
  short* lWk = smem;
  short* lWv = smem + 4096;
  short* lVis = smem + 8192;
  const int tid = threadIdx.x;
  const int lane = tid & 63, w = tid >> 6;
  const int quad = lane >> 4, l16 = lane & 15;
  const int role = w >> 2;          // 0 = k, 1 = v
  const int wq = w & 3, wm = wq >> 1, wn = wq & 1;
  const long n0 = (long)blockIdx.x * 128;  // s
  const long m0 = (long)blockIdx.y * 128;  // i
  const short* vis = visT + blockIdx.z * sV;
  short* kz = kout + blockIdx.z * sKV;
  short* vz = vout + blockIdx.z * sKV;

  float4v acc[4][4];
#pragma unroll
  for (int i = 0; i < 4; i++)
#pragma unroll
    for (int j = 0; j < 4; j++) acc[i][j] = (float4v)0.0f;

  const int srow = tid >> 2;       // 0..127
  const int scol = (tid & 3) * 8;  // 0..24
  const short* lW = role ? lWv : lWk;

  for (int kt = 0; kt < 512; kt += 32) {
    load_lds16(&Wk[(m0 + srow) * 512 + kt + scol], &lWk[tid * 8]);
    load_lds16(&Wv[(m0 + srow) * 512 + kt + scol], &lWv[tid * 8]);
    load_lds16(&vis[(n0 + srow) * 512 + kt + scol], &lVis[tid * 8]);
    __syncthreads();

    short8 af[4], bf[4];
#pragma unroll
    for (int t = 0; t < 4; t++) {
      af[t] = *(const short8*)&lW[(wm * 64 + t * 16 + l16) * 32 + quad * 8];
      bf[t] = *(const short8*)&lVis[(wn * 64 + t * 16 + l16) * 32 + quad * 8];
    }
#pragma unroll
    for (int i = 0; i < 4; i++)
#pragma unroll
      for (int j = 0; j < 4; j++)
        acc[i][j] = mfma16x16x32(af[i], bf[j], acc[i][j]);
    __syncthreads();
  }

  // C/D layout: col(n=s) = lane&15, row(m=i) = quad*4 + reg
  const int cm = wm * 64 + quad * 4;
  const int cn = wn * 64 + l16;

  // v: direct store (i,s); 16-lane 32B runs
  if (role == 1) {
#pragma unroll
    for (int i = 0; i < 4; i++)
#pragma unroll
      for (int j = 0; j < 4; j++) {
        const long gn = n0 + cn + j * 16;
#pragma unroll
        for (int r = 0; r < 4; r++)
          vz[(m0 + cm + i * 16 + r) * 4096 + gn] = f2bf(acc[i][j][r]);
      }
  }

  // k: retile through LDS -> coalesced 256B stores of k[s][i]
  // scratch rows: 64 s-rows x 136 shorts (pad: 2-way max bank conflict)
  short* scratch = smem;  // 64*136 = 8704 shorts <= 12288
#pragma unroll
  for (int h = 0; h < 2; h++) {
    __syncthreads();  // staging LDS dead / previous half consumed
    if (role == 0 && wn == h) {
#pragma unroll
      for (int j = 0; j < 4; j++)
#pragma unroll
        for (int i = 0; i < 4; i++) {
          const int nloc = j * 16 + l16;
          const int m = wm * 64 + i * 16 + quad * 4;
          short4v pk;
#pragma unroll
          for (int r = 0; r < 4; r++) pk[r] = f2bf(acc[i][j][r]);
          *(short4v*)&scratch[nloc * 136 + m] = pk;
        }
    }
    __syncthreads();
    {
      // drain full 64 x 128 tile: 512 threads x 16 shorts (two short8 each)
      const int row = tid >> 3;        // 0..63
      const int off = (tid & 7) * 16;  // 0..112
      short8 v0 = *(const short8*)&scratch[row * 136 + off];
      short8 v1 = *(const short8*)&scratch[row * 136 + off + 8];
      *(short8*)&kz[(n0 + h * 64 + row) * 512 + m0 + off] = v0;
      *(short8*)&kz[(n0 + h * 64 + row) * 512 + m0 + off + 8] = v1;
    }
  }
}

// ---------------- vis fp32 (b,c,s) -> visT bf16 (b,s,c) ----------------
__global__ __launch_bounds__(256) void transpose_f2b(
    const float* __restrict__ vis, short* __restrict__ visT) {
  __shared__ alignas(16) short buf[64][68];
  const int tid = threadIdx.x;
  const long bz = blockIdx.z;
  const long s0 = (long)blockIdx.x * 64;
  const long c0 = (long)blockIdx.y * 64;
  const float* src = vis + bz * 512 * 4096;
  short* dst = visT + bz * 4096 * 512;
  const int tr = tid >> 4;
  const int tc4 = (tid & 15) * 4;
#pragma unroll
  for (int i = 0; i < 4; i++) {
    const int c = tr + i * 16;
    float4v val = *(const float4v*)&src[(c0 + c) * 4096 + s0 + tc4];
    buf[tc4 + 0][c] = f2bf(val[0]);
    buf[tc4 + 1][c] = f2bf(val[1]);
    buf[tc4 + 2][c] = f2bf(val[2]);
    buf[tc4 + 3][c] = f2bf(val[3]);
  }
  __syncthreads();
#pragma unroll
  for (int i = 0; i < 4; i++) {
    const int s = tr + i * 16;
    short4v val = *(const short4v*)&buf[s][tc4];
    *(short4v*)&dst[(s0 + s) * 512 + c0 + tc4] = val;
  }
}

// ---------------- attention partial: block = (head, batch, s-chunk) ----------------
// Each block covers S-range of 4096/NCH = 1024; no-max softmax partials.
__global__ __launch_bounds__(256) void attn_part(
    const short* __restrict__ q, const short* __restrict__ kws,
    const short* __restrict__ vws, float* __restrict__ Opart,
    float* __restrict__ lpart, int b0) {
  const int h = blockIdx.x;
  const int bz = blockIdx.y;
  const int ch = blockIdx.z;
  const int tid = threadIdx.x;
  const int lane = tid & 63, w = tid >> 6;
  const int quad = lane >> 4, l16 = lane & 15;

  __shared__ alignas(16) short lq[64 * 64];
  __shared__ alignas(16) short lk[128 * 64];
  __shared__ alignas(16) short lv[64 * 128];
  __shared__ alignas(16) short lp[64 * 128];
  __shared__ float lsum[64];

  const short* qb = q + ((long)(b0 + bz) * 64) * 512 + h * 64;
  const short* kb = kws + (long)bz * 4096 * 512 + h * 64;
  const short* vb = vws + (long)bz * 512 * 4096 + (long)h * 64 * 4096;

  if (tid < 64) lsum[tid] = 0.0f;
  load_lds16(&qb[(tid >> 3) * 512 + (tid & 7) * 8], &lq[tid * 8]);
  load_lds16(&qb[(32 + (tid >> 3)) * 512 + (tid & 7) * 8], &lq[2048 + tid * 8]);
  __syncthreads();

  short8 aq[4][2];
#pragma unroll
  for (int mt = 0; mt < 4; mt++)
#pragma unroll
    for (int ks = 0; ks < 2; ks++)
      aq[mt][ks] = *(const short8*)&lq[(mt * 16 + l16) * 64 + ks * 32 + quad * 8];

  float4v osc[4];
#pragma unroll
  for (int mt = 0; mt < 4; mt++) osc[mt] = (float4v)0.0f;
  float lrow[4][4] = {};

  const int send = ch * (4096 / NCH) + (4096 / NCH);
  for (int s0 = ch * (4096 / NCH); s0 < send; s0 += 128) {
#pragma unroll
    for (int it = 0; it < 4; it++) {
      const int li = tid + it * 256;
      load_lds16(&kb[(long)(s0 + (li >> 3)) * 512 + (li & 7) * 8], &lk[li * 8]);
    }
#pragma unroll
    for (int it = 0; it < 4; it++) {
      const int li = tid + it * 256;
      load_lds16(&vb[(long)(li >> 4) * 4096 + s0 + (li & 15) * 8], &lv[li * 8]);
    }
    __syncthreads();

    float4v sc[4][2];
#pragma unroll
    for (int mt = 0; mt < 4; mt++)
#pragma unroll
      for (int jn = 0; jn < 2; jn++) sc[mt][jn] = (float4v)0.0f;
#pragma unroll
    for (int ks = 0; ks < 2; ks++) {
      short8 bk[2];
#pragma unroll
      for (int jn = 0; jn < 2; jn++)
        bk[jn] = *(const short8*)&lk[((2 * w + jn) * 16 + l16) * 64 + ks * 32 + quad * 8];
#pragma unroll
      for (int mt = 0; mt < 4; mt++)
#pragma unroll
        for (int jn = 0; jn < 2; jn++)
          sc[mt][jn] = mfma16x16x32(aq[mt][ks], bk[jn], sc[mt][jn]);
    }

#pragma unroll
    for (int mt = 0; mt < 4; mt++)
#pragma unroll
      for (int jn = 0; jn < 2; jn++)
#pragma unroll
        for (int r = 0; r < 4; r++) {
          const float scv = fminf(fmaxf(sc[mt][jn][r], -80.0f), 30.0f);
          const short sp = f2bf(__expf(scv));
          lrow[mt][r] += bf2f(sp);
          lp[(mt * 16 + quad * 4 + r) * 128 + (2 * w + jn) * 16 + l16] = sp;
        }
    __syncthreads();

#pragma unroll
    for (int ks = 0; ks < 4; ks++) {
      const short8 bv = *(const short8*)&lv[(w * 16 + l16) * 128 + ks * 32 + quad * 8];
#pragma unroll
      for (int mt = 0; mt < 4; mt++) {
        const short8 ap = *(const short8*)&lp[(mt * 16 + l16) * 128 + ks * 32 + quad * 8];
        osc[mt] = mfma16x16x32(ap, bv, osc[mt]);
      }
    }
    __syncthreads();
  }

#pragma unroll
  for (int mt = 0; mt < 4; mt++)
#pragma unroll
    for (int r = 0; r < 4; r++) {
      float v = lrow[mt][r];
      v += __shfl_xor(v, 1);
      v += __shfl_xor(v, 2);
      v += __shfl_xor(v, 4);
      v += __shfl_xor(v, 8);
      if (l16 == 0) atomicAdd(&lsum[mt * 16 + quad * 4 + r], v);
    }
  __syncthreads();

  const long bh = bz * 8 + h;
  float* op = Opart + ((bh * NCH + ch) * 64) * 64 + w * 16 + l16;
#pragma unroll
  for (int mt = 0; mt < 4; mt++)
#pragma unroll
    for (int r = 0; r < 4; r++)
      op[(long)(mt * 16 + quad * 4 + r) * 64] = osc[mt][r];
  if (tid < 64) lpart[(bh * NCH + ch) * 64 + tid] = lsum[tid];
}

// ---------------- combine attention partials -> tmp bf16 (b,t,i) ----------------
__global__ __launch_bounds__(256) void attn_combine(
    const float* __restrict__ Opart, const float* __restrict__ lpart,
    short* __restrict__ tmp, int b0, int nbh) {
  const int total = nbh * 4096;
  for (int idx = blockIdx.x * 256 + threadIdx.x; idx < total;
       idx += gridDim.x * 256) {
    const int bh = idx >> 12;
    const int td = idx & 4095;
    const int t = td >> 6, d = td & 63;
    float o = 0.0f, l = 0.0f;
#pragma unroll
    for (int c = 0; c < NCH; c++) {
      o += Opart[((long)bh * NCH + c) * 4096 + td];
      l += lpart[(bh * NCH + c) * 64 + t];
    }
    const int b = b0 + (bh >> 3), h = bh & 7;
    tmp[((long)b * 64 + t) * 512 + h * 64 + d] = f2bf(o / l);
  }
}

// ---------------- launch ----------------
extern "C" void kernel_launch(void* const* d_in, const int* in_sizes, int n_in,
                              void* d_out, int out_size, void* d_ws, size_t ws_size,
                              hipStream_t stream) {
  (void)in_sizes; (void)n_in; (void)out_size;
  const float* vis = (const float*)d_in[0];   // [16][512][4096] fp32
  const float* lang = (const float*)d_in[1];  // [16][64][512]  fp32
  const float* Wq = (const float*)d_in[3];    // [512][512] fp32
  const float* Wk = (const float*)d_in[4];
  const float* Wv = (const float*)d_in[5];
  const float* Wo = (const float*)d_in[6];
  float* out = (float*)d_out;                 // [16][64][512] fp32

  char* ws = (char*)d_ws;
  const size_t MB = 1 << 20;
  short* q_ws = (short*)(ws + 0 * MB);
  short* tmp_ws = (short*)(ws + 1 * MB);
  short* langb = (short*)(ws + 2 * MB);
  short* Wqb = (short*)(ws + 3 * MB);
  short* Wkb = (short*)(ws + 3 * MB + 512 * 1024);
  short* Wvb = (short*)(ws + 4 * MB);
  short* Wob = (short*)(ws + 4 * MB + 512 * 1024);
  char* grp = ws + 5 * MB;

  const long batch_elems = 4096l * 512;
  int g = 16;
  const int cands[5] = {1, 2, 4, 8, 16};
  for (int ci = 0; ci < 5; ci++) {
    const size_t need = 5 * MB + 3ull * (16 / cands[ci]) * batch_elems * 2;
    if (need <= ws_size) { g = cands[ci]; break; }
  }
  const int Bg = 16 / g;
  short* visT = (short*)grp;                    // [Bg][4096][512]
  short* k_ws = visT + (long)Bg * batch_elems;  // [Bg][4096][512] (s,i)
  short* v_ws = k_ws + (long)Bg * batch_elems;  // [Bg][512][4096] (i,s)
  // attn partials alias visT (dead by attn time)
  float* Opart = (float*)visT;
  float* lptr = Opart + (long)Bg * 8 * NCH * 4096;

  convert5<<<dim3(128, 5), 256, 0, stream>>>(lang, langb, Wq, Wqb, Wk, Wkb,
                                             Wv, Wvb, Wo, Wob);

  // q = SCALE * lang @ Wq^T
  gemm_nt<0><<<dim3(4, 8), 256, 0, stream>>>(langb, Wqb, q_ws, 512, 512, 0.125f);

  for (int gi = 0; gi < g; gi++) {
    const int b0 = gi * Bg;
    transpose_f2b<<<dim3(64, 8, Bg), 256, 0, stream>>>(vis + (long)b0 * batch_elems, visT);
    gemm_kv<<<dim3(32, 4, Bg), 512, 0, stream>>>(Wkb, Wvb, visT, batch_elems,
                                                 k_ws, v_ws, batch_elems);
    attn_part<<<dim3(8, Bg, NCH), 256, 0, stream>>>(q_ws, k_ws, v_ws, Opart, lptr, b0);
    attn_combine<<<512, 256, 0, stream>>>(Opart, lptr, tmp_ws, b0, Bg * 8);
  }

  // out = tmp @ Wo^T, fp32 epilogue
  gemm_nt<1><<<dim3(4, 8), 256, 0, stream>>>(tmp_ws, Wob, out, 512, 512, 1.0f);
}

// Round 7
// 389.299 us; speedup vs baseline: 1.0451x; 1.0451x over previous
//
#include <hip/hip_runtime.h>
#include <stdint.h>

// ---------------- common helpers ----------------
typedef __attribute__((ext_vector_type(8))) short short8;
typedef __attribute__((ext_vector_type(4))) short short4v;
typedef __attribute__((ext_vector_type(4))) float float4v;
typedef __attribute__((ext_vector_type(8))) __bf16 bf16x8;

#define NCH 4  // attention S-dim split factor

__device__ __forceinline__ float4v mfma16x16x32(short8 a, short8 b, float4v c) {
  return __builtin_amdgcn_mfma_f32_16x16x32_bf16(
      __builtin_bit_cast(bf16x8, a), __builtin_bit_cast(bf16x8, b), c, 0, 0, 0);
}

// float -> bf16 (RNE), as raw short
__device__ __forceinline__ short f2bf(float f) {
  uint32_t u = __builtin_bit_cast(uint32_t, f);
  u += 0x7fffu + ((u >> 16) & 1u);
  return (short)(u >> 16);
}

__device__ __forceinline__ float bf2f(short s) {
  return __builtin_bit_cast(float, ((uint32_t)(uint16_t)s) << 16);
}

// async 16B global->LDS. LDS dst = wave-uniform base + lane*16 at all sites.
__device__ __forceinline__ void load_lds16(const short* g, short* l) {
  __builtin_amdgcn_global_load_lds(
      (const __attribute__((address_space(1))) void*)g,
      (__attribute__((address_space(3))) void*)l, 16, 0, 0);
}

// ---------------- fused fp32 -> bf16 for lang + 4 weights ----------------
__global__ __launch_bounds__(256) void convert5(
    const float* __restrict__ sl, short* __restrict__ dl,
    const float* __restrict__ s1, short* __restrict__ d1,
    const float* __restrict__ s2, short* __restrict__ d2,
    const float* __restrict__ s3, short* __restrict__ d3,
    const float* __restrict__ s4, short* __restrict__ d4) {
  const float* src; short* dst; int n4;
  switch (blockIdx.y) {
    case 0: src = sl; dst = dl; n4 = 131072; break;
    case 1: src = s1; dst = d1; n4 = 65536; break;
    case 2: src = s2; dst = d2; n4 = 65536; break;
    case 3: src = s3; dst = d3; n4 = 65536; break;
    default: src = s4; dst = d4; n4 = 65536; break;
  }
  const int stride = gridDim.x * blockDim.x;
  for (int i = blockIdx.x * blockDim.x + threadIdx.x; i < n4; i += stride) {
    float4v v = *(const float4v*)(src + (long)i * 4);
    short4v o;
#pragma unroll
    for (int r = 0; r < 4; r++) o[r] = f2bf(v[r]);
    *(short4v*)(dst + (long)i * 4) = o;
  }
}

// ---------------- small NT GEMM (q / out projections) ----------------
// C[m,n] = scale * sum_k A[m,k]*B[n,k]; 128x128 tile, BK=32, 4 waves.
// LDS XOR-swizzle: slot (row, c) holds global chunk c ^ ((row>>1)&3); staging
// permutes the SOURCE chunk (global_load_lds slot is lane-fixed), reads XOR it
// back. Makes every b128 16-lane phase span all 8 bank-quads (2-way = free).
// OUT_F32=1: C fp32; else bf16.
template <int OUT_F32>
__global__ __launch_bounds__(256) void gemm_nt(
    const short* __restrict__ A, const short* __restrict__ B,
    void* __restrict__ C, int K, int ldc, float scale) {
  __shared__ alignas(16) short lA[128 * 32];
  __shared__ alignas(16) short lB[128 * 32];
  const int tid = threadIdx.x;
  const int lane = tid & 63, w = tid >> 6;
  const int quad = lane >> 4, l16 = lane & 15;
  const int wm = w >> 1, wn = w & 1;
  const long m0 = (long)blockIdx.y * 128, n0 = (long)blockIdx.x * 128;

  float4v acc[4][4];
#pragma unroll
  for (int i = 0; i < 4; i++)
#pragma unroll
    for (int j = 0; j < 4; j++) acc[i][j] = (float4v)0.0f;

  const int srow = tid >> 2;  // 0..63 (also used at +64)
  const int scol = (((tid & 3) ^ ((srow >> 1) & 3))) * 8;  // swizzled source chunk

  for (int kt = 0; kt < K; kt += 32) {
    load_lds16(&A[(m0 + srow) * K + kt + scol], &lA[tid * 8]);
    load_lds16(&A[(m0 + 64 + srow) * K + kt + scol], &lA[2048 + tid * 8]);
    load_lds16(&B[(n0 + srow) * K + kt + scol], &lB[tid * 8]);
    load_lds16(&B[(n0 + 64 + srow) * K + kt + scol], &lB[2048 + tid * 8]);
    __syncthreads();

    short8 af[4], bf[4];
#pragma unroll
    for (int t = 0; t < 4; t++) {
      const int ra = wm * 64 + t * 16 + l16;
      const int rb = wn * 64 + t * 16 + l16;
      af[t] = *(const short8*)&lA[ra * 32 + ((quad ^ ((ra >> 1) & 3)) * 8)];
      bf[t] = *(const short8*)&lB[rb * 32 + ((quad ^ ((rb >> 1) & 3)) * 8)];
    }
#pragma unroll
    for (int i = 0; i < 4; i++)
#pragma unroll
      for (int j = 0; j < 4; j++)
        acc[i][j] = mfma16x16x32(af[i], bf[j], acc[i][j]);
    __syncthreads();
  }

  const int cm = wm * 64 + quad * 4;
  const int cn = wn * 64 + l16;
  if (OUT_F32) {
    float* Cf = (float*)C;
#pragma unroll
    for (int i = 0; i < 4; i++)
#pragma unroll
      for (int j = 0; j < 4; j++) {
        const long gn = n0 + cn + j * 16;
#pragma unroll
        for (int r = 0; r < 4; r++)
          Cf[(m0 + cm + i * 16 + r) * (long)ldc + gn] = acc[i][j][r] * scale;
      }
  } else {
    short* Cs = (short*)C;
#pragma unroll
    for (int i = 0; i < 4; i++)
#pragma unroll
      for (int j = 0; j < 4; j++) {
        const long gn = n0 + cn + j * 16;
#pragma unroll
        for (int r = 0; r < 4; r++)
          Cs[(m0 + cm + i * 16 + r) * (long)ldc + gn] = f2bf(acc[i][j][r] * scale);
      }
  }
}

// ---------------- fused KV projection ----------------
// k[s][i] (TRANS, coalesced via LDS retile) and v[i][s] from shared visT tile.
// 512 threads = 8 waves: w0..3 -> k (Wk), w4..7 -> v (Wv). Same XOR-swizzle as
// gemm_nt on all three staged tiles. grid=(S/128, I/128, Bg).
__global__ __launch_bounds__(512) void gemm_kv(
    const short* __restrict__ Wk, const short* __restrict__ Wv,
    const short* __restrict__ visT, long sV,
    short* __restrict__ kout, short* __restrict__ vout, long sKV) {
  __shared__ alignas(16) short smem[12288];  // lWk | lWv | lVis; scratch aliases
  short* lWk = smem;
  short* lWv = smem + 4096;
  short* lVis = smem + 8192;
  const int tid = threadIdx.x;
  const int lane = tid & 63, w = tid >> 6;
  const int quad = lane >> 4, l16 = lane & 15;
  const int role = w >> 2;          // 0 = k, 1 = v
  const int wq = w & 3, wm = wq >> 1, wn = wq & 1;
  const long n0 = (long)blockIdx.x * 128;  // s
  const long m0 = (long)blockIdx.y * 128;  // i
  const short* vis = visT + blockIdx.z * sV;
  short* kz = kout + blockIdx.z * sKV;
  short* vz = vout + blockIdx.z * sKV;

  float4v acc[4][4];
#pragma unroll
  for (int i = 0; i < 4; i++)
#pragma unroll
    for (int j = 0; j < 4; j++) acc[i][j] = (float4v)0.0f;

  const int srow = tid >> 2;  // 0..127
  const int scol = (((tid & 3) ^ ((srow >> 1) & 3))) * 8;  // swizzled source chunk
  const short* lW = role ? lWv : lWk;

  for (int kt = 0; kt < 512; kt += 32) {
    load_lds16(&Wk[(m0 + srow) * 512 + kt + scol], &lWk[tid * 8]);
    load_lds16(&Wv[(m0 + srow) * 512 + kt + scol], &lWv[tid * 8]);
    load_lds16(&vis[(n0 + srow) * 512 + kt + scol], &lVis[tid * 8]);
    __syncthreads();

    short8 af[4], bf[4];
#pragma unroll
    for (int t = 0; t < 4; t++) {
      const int ra = wm * 64 + t * 16 + l16;
      const int rb = wn * 64 + t * 16 + l16;
      af[t] = *(const short8*)&lW[ra * 32 + ((quad ^ ((ra >> 1) & 3)) * 8)];
      bf[t] = *(const short8*)&lVis[rb * 32 + ((quad ^ ((rb >> 1) & 3)) * 8)];
    }
#pragma unroll
    for (int i = 0; i < 4; i++)
#pragma unroll
      for (int j = 0; j < 4; j++)
        acc[i][j] = mfma16x16x32(af[i], bf[j], acc[i][j]);
    __syncthreads();
  }

  // C/D layout: col(n=s) = lane&15, row(m=i) = quad*4 + reg
  const int cm = wm * 64 + quad * 4;
  const int cn = wn * 64 + l16;

  // v: direct store (i,s)
  if (role == 1) {
#pragma unroll
    for (int i = 0; i < 4; i++)
#pragma unroll
      for (int j = 0; j < 4; j++) {
        const long gn = n0 + cn + j * 16;
#pragma unroll
        for (int r = 0; r < 4; r++)
          vz[(m0 + cm + i * 16 + r) * 4096 + gn] = f2bf(acc[i][j][r]);
      }
  }

  // k: retile through LDS -> coalesced 256B stores of k[s][i]
  short* scratch = smem;  // 64 rows x 136 shorts = 8704 <= 12288
#pragma unroll
  for (int h = 0; h < 2; h++) {
    __syncthreads();
    if (role == 0 && wn == h) {
#pragma unroll
      for (int j = 0; j < 4; j++)
#pragma unroll
        for (int i = 0; i < 4; i++) {
          const int nloc = j * 16 + l16;
          const int m = wm * 64 + i * 16 + quad * 4;
          short4v pk;
#pragma unroll
          for (int r = 0; r < 4; r++) pk[r] = f2bf(acc[i][j][r]);
          *(short4v*)&scratch[nloc * 136 + m] = pk;
        }
    }
    __syncthreads();
    {
      // drain full 64 x 128 tile: 512 threads x 16 shorts
      const int row = tid >> 3;        // 0..63
      const int off = (tid & 7) * 16;  // 0..112
      short8 v0 = *(const short8*)&scratch[row * 136 + off];
      short8 v1 = *(const short8*)&scratch[row * 136 + off + 8];
      *(short8*)&kz[(n0 + h * 64 + row) * 512 + m0 + off] = v0;
      *(short8*)&kz[(n0 + h * 64 + row) * 512 + m0 + off + 8] = v1;
    }
  }
}

// ---------------- vis fp32 (b,c,s) -> visT bf16 (b,s,c) ----------------
__global__ __launch_bounds__(256) void transpose_f2b(
    const float* __restrict__ vis, short* __restrict__ visT) {
  __shared__ alignas(16) short buf[64][68];
  const int tid = threadIdx.x;
  const long bz = blockIdx.z;
  const long s0 = (long)blockIdx.x * 64;
  const long c0 = (long)blockIdx.y * 64;
  const float* src = vis + bz * 512 * 4096;
  short* dst = visT + bz * 4096 * 512;
  const int tr = tid >> 4;
  const int tc4 = (tid & 15) * 4;
#pragma unroll
  for (int i = 0; i < 4; i++) {
    const int c = tr + i * 16;
    float4v val = *(const float4v*)&src[(c0 + c) * 4096 + s0 + tc4];
    buf[tc4 + 0][c] = f2bf(val[0]);
    buf[tc4 + 1][c] = f2bf(val[1]);
    buf[tc4 + 2][c] = f2bf(val[2]);
    buf[tc4 + 3][c] = f2bf(val[3]);
  }
  __syncthreads();
#pragma unroll
  for (int i = 0; i < 4; i++) {
    const int s = tr + i * 16;
    short4v val = *(const short4v*)&buf[s][tc4];
    *(short4v*)&dst[(s0 + s) * 512 + c0 + tc4] = val;
  }
}

// ---------------- attention partial: block = (head, batch, s-chunk) ----------------
// Each block covers 4096/NCH s-positions; no-max softmax partials.
// All LDS tiles XOR-swizzled: slot (row, c) holds chunk c ^ (row&7).
__global__ __launch_bounds__(256) void attn_part(
    const short* __restrict__ q, const short* __restrict__ kws,
    const short* __restrict__ vws, float* __restrict__ Opart,
    float* __restrict__ lpart, int b0) {
  const int h = blockIdx.x;
  const int bz = blockIdx.y;
  const int ch = blockIdx.z;
  const int tid = threadIdx.x;
  const int lane = tid & 63, w = tid >> 6;
  const int quad = lane >> 4, l16 = lane & 15;

  __shared__ alignas(16) short lq[64 * 64];
  __shared__ alignas(16) short lk[128 * 64];
  __shared__ alignas(16) short lv[64 * 128];
  __shared__ alignas(16) short lp[64 * 128];
  __shared__ float lsum[64];

  const short* qb = q + ((long)(b0 + bz) * 64) * 512 + h * 64;
  const short* kb = kws + (long)bz * 4096 * 512 + h * 64;
  const short* vb = vws + (long)bz * 512 * 4096 + (long)h * 64 * 4096;

  if (tid < 64) lsum[tid] = 0.0f;
  {
    // lq: 64 rows x 8 chunks; slot (r, c) <- global chunk c ^ (r&7)
    const int qr = tid >> 3;
    const int qc = ((tid & 7) ^ (qr & 7)) * 8;
    load_lds16(&qb[qr * 512 + qc], &lq[tid * 8]);
    load_lds16(&qb[(32 + qr) * 512 + qc], &lq[2048 + tid * 8]);  // (32+qr)&7 == qr&7... only if qr<8
  }
  __syncthreads();

  short8 aq[4][2];
#pragma unroll
  for (int mt = 0; mt < 4; mt++)
#pragma unroll
    for (int ks = 0; ks < 2; ks++) {
      const int ra = mt * 16 + l16;
      aq[mt][ks] = *(const short8*)&lq[ra * 64 + (((ks * 4 + quad) ^ (ra & 7)) * 8)];
    }

  float4v osc[4];
#pragma unroll
  for (int mt = 0; mt < 4; mt++) osc[mt] = (float4v)0.0f;
  float lrow[4][4] = {};

  const int send = ch * (4096 / NCH) + (4096 / NCH);
  for (int s0 = ch * (4096 / NCH); s0 < send; s0 += 128) {
#pragma unroll
    for (int it = 0; it < 4; it++) {
      const int li = tid + it * 256;
      const int kr = li >> 3;                       // 0..127
      const int kc = ((li & 7) ^ (kr & 7)) * 8;     // swizzled source chunk
      load_lds16(&kb[(long)(s0 + kr) * 512 + kc], &lk[li * 8]);
    }
#pragma unroll
    for (int it = 0; it < 4; it++) {
      const int li = tid + it * 256;
      const int vr = li >> 4;                        // 0..63 (d-row)
      const int vc = ((li & 15) ^ (vr & 7)) * 8;     // swizzled source chunk
      load_lds16(&vb[(long)vr * 4096 + s0 + vc], &lv[li * 8]);
    }
    __syncthreads();

    float4v sc[4][2];
#pragma unroll
    for (int mt = 0; mt < 4; mt++)
#pragma unroll
      for (int jn = 0; jn < 2; jn++) sc[mt][jn] = (float4v)0.0f;
#pragma unroll
    for (int ks = 0; ks < 2; ks++) {
      short8 bk[2];
#pragma unroll
      for (int jn = 0; jn < 2; jn++) {
        const int rb = (2 * w + jn) * 16 + l16;
        bk[jn] = *(const short8*)&lk[rb * 64 + (((ks * 4 + quad) ^ (rb & 7)) * 8)];
      }
#pragma unroll
      for (int mt = 0; mt < 4; mt++)
#pragma unroll
        for (int jn = 0; jn < 2; jn++)
          sc[mt][jn] = mfma16x16x32(aq[mt][ks], bk[jn], sc[mt][jn]);
    }

    // p = exp(clamped score); bf16-quantized row sums; park p in lp with the
    // same row-XOR swizzle (write side: slot = (col>>3) ^ (row&7)).
#pragma unroll
    for (int mt = 0; mt < 4; mt++)
#pragma unroll
      for (int jn = 0; jn < 2; jn++)
#pragma unroll
        for (int r = 0; r < 4; r++) {
          const float scv = fminf(fmaxf(sc[mt][jn][r], -80.0f), 30.0f);
          const short sp = f2bf(__expf(scv));
          lrow[mt][r] += bf2f(sp);
          const int rowp = mt * 16 + quad * 4 + r;
          const int col = (2 * w + jn) * 16 + l16;
          lp[rowp * 128 + (((col >> 3) ^ (rowp & 7)) * 8) + (col & 7)] = sp;
        }
    __syncthreads();

#pragma unroll
    for (int ks = 0; ks < 4; ks++) {
      const int rv = w * 16 + l16;
      const short8 bv = *(const short8*)&lv[rv * 128 + (((ks * 4 + quad) ^ (rv & 7)) * 8)];
#pragma unroll
      for (int mt = 0; mt < 4; mt++) {
        const int rp = mt * 16 + l16;
        const short8 ap = *(const short8*)&lp[rp * 128 + (((ks * 4 + quad) ^ (rp & 7)) * 8)];
        osc[mt] = mfma16x16x32(ap, bv, osc[mt]);
      }
    }
    __syncthreads();
  }

#pragma unroll
  for (int mt = 0; mt < 4; mt++)
#pragma unroll
    for (int r = 0; r < 4; r++) {
      float v = lrow[mt][r];
      v += __shfl_xor(v, 1);
      v += __shfl_xor(v, 2);
      v += __shfl_xor(v, 4);
      v += __shfl_xor(v, 8);
      if (l16 == 0) atomicAdd(&lsum[mt * 16 + quad * 4 + r], v);
    }
  __syncthreads();

  const long bh = bz * 8 + h;
  float* op = Opart + ((bh * NCH + ch) * 64) * 64 + w * 16 + l16;
#pragma unroll
  for (int mt = 0; mt < 4; mt++)
#pragma unroll
    for (int r = 0; r < 4; r++)
      op[(long)(mt * 16 + quad * 4 + r) * 64] = osc[mt][r];
  if (tid < 64) lpart[(bh * NCH + ch) * 64 + tid] = lsum[tid];
}

// ---------------- combine attention partials -> tmp bf16 (b,t,i) ----------------
__global__ __launch_bounds__(256) void attn_combine(
    const float* __restrict__ Opart, const float* __restrict__ lpart,
    short* __restrict__ tmp, int b0, int nbh) {
  const int total = nbh * 4096;
  for (int idx = blockIdx.x * 256 + threadIdx.x; idx < total;
       idx += gridDim.x * 256) {
    const int bh = idx >> 12;
    const int td = idx & 4095;
    const int t = td >> 6, d = td & 63;
    float o = 0.0f, l = 0.0f;
#pragma unroll
    for (int c = 0; c < NCH; c++) {
      o += Opart[((long)bh * NCH + c) * 4096 + td];
      l += lpart[(bh * NCH + c) * 64 + t];
    }
    const int b = b0 + (bh >> 3), h = bh & 7;
    tmp[((long)b * 64 + t) * 512 + h * 64 + d] = f2bf(o / l);
  }
}

// ---------------- launch ----------------
extern "C" void kernel_launch(void* const* d_in, const int* in_sizes, int n_in,
                              void* d_out, int out_size, void* d_ws, size_t ws_size,
                              hipStream_t stream) {
  (void)in_sizes; (void)n_in; (void)out_size;
  const float* vis = (const float*)d_in[0];   // [16][512][4096] fp32
  const float* lang = (const float*)d_in[1];  // [16][64][512]  fp32
  const float* Wq = (const float*)d_in[3];    // [512][512] fp32
  const float* Wk = (const float*)d_in[4];
  const float* Wv = (const float*)d_in[5];
  const float* Wo = (const float*)d_in[6];
  float* out = (float*)d_out;                 // [16][64][512] fp32

  char* ws = (char*)d_ws;
  const size_t MB = 1 << 20;
  short* q_ws = (short*)(ws + 0 * MB);
  short* tmp_ws = (short*)(ws + 1 * MB);
  short* langb = (short*)(ws + 2 * MB);
  short* Wqb = (short*)(ws + 3 * MB);
  short* Wkb = (short*)(ws + 3 * MB + 512 * 1024);
  short* Wvb = (short*)(ws + 4 * MB);
  short* Wob = (short*)(ws + 4 * MB + 512 * 1024);
  char* grp = ws + 5 * MB;

  const long batch_elems = 4096l * 512;
  int g = 16;
  const int cands[5] = {1, 2, 4, 8, 16};
  for (int ci = 0; ci < 5; ci++) {
    const size_t need = 5 * MB + 3ull * (16 / cands[ci]) * batch_elems * 2;
    if (need <= ws_size) { g = cands[ci]; break; }
  }
  const int Bg = 16 / g;
  short* visT = (short*)grp;                    // [Bg][4096][512]
  short* k_ws = visT + (long)Bg * batch_elems;  // [Bg][4096][512] (s,i)
  short* v_ws = k_ws + (long)Bg * batch_elems;  // [Bg][512][4096] (i,s)
  // attn partials alias visT (dead by attn time)
  float* Opart = (float*)visT;
  float* lptr = Opart + (long)Bg * 8 * NCH * 4096;

  convert5<<<dim3(128, 5), 256, 0, stream>>>(lang, langb, Wq, Wqb, Wk, Wkb,
                                             Wv, Wvb, Wo, Wob);

  // q = SCALE * lang @ Wq^T
  gemm_nt<0><<<dim3(4, 8), 256, 0, stream>>>(langb, Wqb, q_ws, 512, 512, 0.125f);

  for (int gi = 0; gi < g; gi++) {
    const int b0 = gi * Bg;
    transpose_f2b<<<dim3(64, 8, Bg), 256, 0, stream>>>(vis + (long)b0 * batch_elems, visT);
    gemm_kv<<<dim3(32, 4, Bg), 512, 0, stream>>>(Wkb, Wvb, visT, batch_elems,
                                                 k_ws, v_ws, batch_elems);
    attn_part<<<dim3(8, Bg, NCH), 256, 0, stream>>>(q_ws, k_ws, v_ws, Opart, lptr, b0);
    attn_combine<<<512, 256, 0, stream>>>(Opart, lptr, tmp_ws, b0, Bg * 8);
  }

  // out = tmp @ Wo^T, fp32 epilogue
  gemm_nt<1><<<dim3(4, 8), 256, 0, stream>>>(tmp_ws, Wob, out, 512, 512, 1.0f);
}

// Round 8
// 379.700 us; speedup vs baseline: 1.0715x; 1.0253x over previous
//
#include <hip/hip_runtime.h>
#include <stdint.h>

// ---------------- common helpers ----------------
typedef __attribute__((ext_vector_type(8))) short short8;
typedef __attribute__((ext_vector_type(4))) short short4v;
typedef __attribute__((ext_vector_type(4))) float float4v;
typedef __attribute__((ext_vector_type(8))) __bf16 bf16x8;

#define NCH 4  // attention S-dim split factor

__device__ __forceinline__ float4v mfma16x16x32(short8 a, short8 b, float4v c) {
  return __builtin_amdgcn_mfma_f32_16x16x32_bf16(
      __builtin_bit_cast(bf16x8, a), __builtin_bit_cast(bf16x8, b), c, 0, 0, 0);
}

// float -> bf16 (RNE), as raw short
__device__ __forceinline__ short f2bf(float f) {
  uint32_t u = __builtin_bit_cast(uint32_t, f);
  u += 0x7fffu + ((u >> 16) & 1u);
  return (short)(u >> 16);
}

__device__ __forceinline__ float bf2f(short s) {
  return __builtin_bit_cast(float, ((uint32_t)(uint16_t)s) << 16);
}

// async 16B global->LDS. LDS dst = wave-uniform base + lane*16 at all sites.
__device__ __forceinline__ void load_lds16(const short* g, short* l) {
  __builtin_amdgcn_global_load_lds(
      (const __attribute__((address_space(1))) void*)g,
      (__attribute__((address_space(3))) void*)l, 16, 0, 0);
}

// ---------------- fused fp32 -> bf16 for lang + 4 weights ----------------
__global__ __launch_bounds__(256) void convert5(
    const float* __restrict__ sl, short* __restrict__ dl,
    const float* __restrict__ s1, short* __restrict__ d1,
    const float* __restrict__ s2, short* __restrict__ d2,
    const float* __restrict__ s3, short* __restrict__ d3,
    const float* __restrict__ s4, short* __restrict__ d4) {
  const float* src; short* dst; int n4;
  switch (blockIdx.y) {
    case 0: src = sl; dst = dl; n4 = 131072; break;
    case 1: src = s1; dst = d1; n4 = 65536; break;
    case 2: src = s2; dst = d2; n4 = 65536; break;
    case 3: src = s3; dst = d3; n4 = 65536; break;
    default: src = s4; dst = d4; n4 = 65536; break;
  }
  const int stride = gridDim.x * blockDim.x;
  for (int i = blockIdx.x * blockDim.x + threadIdx.x; i < n4; i += stride) {
    float4v v = *(const float4v*)(src + (long)i * 4);
    short4v o;
#pragma unroll
    for (int r = 0; r < 4; r++) o[r] = f2bf(v[r]);
    *(short4v*)(dst + (long)i * 4) = o;
  }
}

// ---------------- small NT GEMM (q / out projections) ----------------
// C[m,n] = scale * sum_k A[m,k]*B[n,k]; 128x128 tile, BK=32, 4 waves.
// XOR-swizzled LDS (slot (row,c) holds chunk c ^ ((row>>1)&3)).
// K-loop: prefetch-reordered — stage(t+1) issued AFTER all waves pulled tile t
// into regs, so load latency overlaps MFMA(t). Single buffer, race-free.
template <int OUT_F32>
__global__ __launch_bounds__(256) void gemm_nt(
    const short* __restrict__ A, const short* __restrict__ B,
    void* __restrict__ C, int K, int ldc, float scale) {
  __shared__ alignas(16) short lA[128 * 32];
  __shared__ alignas(16) short lB[128 * 32];
  const int tid = threadIdx.x;
  const int lane = tid & 63, w = tid >> 6;
  const int quad = lane >> 4, l16 = lane & 15;
  const int wm = w >> 1, wn = w & 1;
  const long m0 = (long)blockIdx.y * 128, n0 = (long)blockIdx.x * 128;

  float4v acc[4][4];
#pragma unroll
  for (int i = 0; i < 4; i++)
#pragma unroll
    for (int j = 0; j < 4; j++) acc[i][j] = (float4v)0.0f;

  const int srow = tid >> 2;  // 0..63 (also used at +64)
  const int scol = (((tid & 3) ^ ((srow >> 1) & 3))) * 8;  // swizzled source chunk

  // prologue: stage tile 0
  load_lds16(&A[(m0 + srow) * K + scol], &lA[tid * 8]);
  load_lds16(&A[(m0 + 64 + srow) * K + scol], &lA[2048 + tid * 8]);
  load_lds16(&B[(n0 + srow) * K + scol], &lB[tid * 8]);
  load_lds16(&B[(n0 + 64 + srow) * K + scol], &lB[2048 + tid * 8]);

  for (int kt = 0; kt < K; kt += 32) {
    __syncthreads();  // stage(kt) landed (vmcnt drained here)

    short8 af[4], bf[4];
#pragma unroll
    for (int t = 0; t < 4; t++) {
      const int ra = wm * 64 + t * 16 + l16;
      const int rb = wn * 64 + t * 16 + l16;
      af[t] = *(const short8*)&lA[ra * 32 + ((quad ^ ((ra >> 1) & 3)) * 8)];
      bf[t] = *(const short8*)&lB[rb * 32 + ((quad ^ ((rb >> 1) & 3)) * 8)];
    }
    __syncthreads();  // all waves done reading lA/lB

    if (kt + 32 < K) {  // stage(kt+32) overlaps the MFMAs below
      load_lds16(&A[(m0 + srow) * K + kt + 32 + scol], &lA[tid * 8]);
      load_lds16(&A[(m0 + 64 + srow) * K + kt + 32 + scol], &lA[2048 + tid * 8]);
      load_lds16(&B[(n0 + srow) * K + kt + 32 + scol], &lB[tid * 8]);
      load_lds16(&B[(n0 + 64 + srow) * K + kt + 32 + scol], &lB[2048 + tid * 8]);
    }
#pragma unroll
    for (int i = 0; i < 4; i++)
#pragma unroll
      for (int j = 0; j < 4; j++)
        acc[i][j] = mfma16x16x32(af[i], bf[j], acc[i][j]);
  }

  const int cm = wm * 64 + quad * 4;
  const int cn = wn * 64 + l16;
  if (OUT_F32) {
    float* Cf = (float*)C;
#pragma unroll
    for (int i = 0; i < 4; i++)
#pragma unroll
      for (int j = 0; j < 4; j++) {
        const long gn = n0 + cn + j * 16;
#pragma unroll
        for (int r = 0; r < 4; r++)
          Cf[(m0 + cm + i * 16 + r) * (long)ldc + gn] = acc[i][j][r] * scale;
      }
  } else {
    short* Cs = (short*)C;
#pragma unroll
    for (int i = 0; i < 4; i++)
#pragma unroll
      for (int j = 0; j < 4; j++) {
        const long gn = n0 + cn + j * 16;
#pragma unroll
        for (int r = 0; r < 4; r++)
          Cs[(m0 + cm + i * 16 + r) * (long)ldc + gn] = f2bf(acc[i][j][r] * scale);
      }
  }
}

// ---------------- fused KV projection ----------------
// k[s][i] (TRANS via LDS retile) and v[i][s] from shared visT tile.
// 512 threads = 8 waves: w0..3 -> k, w4..7 -> v. XOR-swizzled LDS.
// K-loop prefetch-reordered (see gemm_nt). grid=(S/128, I/128, Bg).
__global__ __launch_bounds__(512) void gemm_kv(
    const short* __restrict__ Wk, const short* __restrict__ Wv,
    const short* __restrict__ visT, long sV,
    short* __restrict__ kout, short* __restrict__ vout, long sKV) {
  __shared__ alignas(16) short smem[12288];  // lWk | lWv | lVis; scratch aliases
  short* lWk = smem;
  short* lWv = smem + 4096;
  short* lVis = smem + 8192;
  const int tid = threadIdx.x;
  const int lane = tid & 63, w = tid >> 6;
  const int quad = lane >> 4, l16 = lane & 15;
  const int role = w >> 2;          // 0 = k, 1 = v
  const int wq = w & 3, wm = wq >> 1, wn = wq & 1;
  const long n0 = (long)blockIdx.x * 128;  // s
  const long m0 = (long)blockIdx.y * 128;  // i
  const short* vis = visT + blockIdx.z * sV;
  short* kz = kout + blockIdx.z * sKV;
  short* vz = vout + blockIdx.z * sKV;

  float4v acc[4][4];
#pragma unroll
  for (int i = 0; i < 4; i++)
#pragma unroll
    for (int j = 0; j < 4; j++) acc[i][j] = (float4v)0.0f;

  const int srow = tid >> 2;  // 0..127
  const int scol = (((tid & 3) ^ ((srow >> 1) & 3))) * 8;  // swizzled source chunk
  const short* lW = role ? lWv : lWk;

  // prologue: stage tile 0
  load_lds16(&Wk[(m0 + srow) * 512 + scol], &lWk[tid * 8]);
  load_lds16(&Wv[(m0 + srow) * 512 + scol], &lWv[tid * 8]);
  load_lds16(&vis[(n0 + srow) * 512 + scol], &lVis[tid * 8]);

  for (int kt = 0; kt < 512; kt += 32) {
    __syncthreads();  // stage(kt) landed

    short8 af[4], bf[4];
#pragma unroll
    for (int t = 0; t < 4; t++) {
      const int ra = wm * 64 + t * 16 + l16;
      const int rb = wn * 64 + t * 16 + l16;
      af[t] = *(const short8*)&lW[ra * 32 + ((quad ^ ((ra >> 1) & 3)) * 8)];
      bf[t] = *(const short8*)&lVis[rb * 32 + ((quad ^ ((rb >> 1) & 3)) * 8)];
    }
    __syncthreads();  // all waves done reading

    if (kt + 32 < 512) {  // stage(kt+32) overlaps MFMAs
      load_lds16(&Wk[(m0 + srow) * 512 + kt + 32 + scol], &lWk[tid * 8]);
      load_lds16(&Wv[(m0 + srow) * 512 + kt + 32 + scol], &lWv[tid * 8]);
      load_lds16(&vis[(n0 + srow) * 512 + kt + 32 + scol], &lVis[tid * 8]);
    }
#pragma unroll
    for (int i = 0; i < 4; i++)
#pragma unroll
      for (int j = 0; j < 4; j++)
        acc[i][j] = mfma16x16x32(af[i], bf[j], acc[i][j]);
  }

  // C/D layout: col(n=s) = lane&15, row(m=i) = quad*4 + reg
  const int cm = wm * 64 + quad * 4;
  const int cn = wn * 64 + l16;

  // v: direct store (i,s)
  if (role == 1) {
#pragma unroll
    for (int i = 0; i < 4; i++)
#pragma unroll
      for (int j = 0; j < 4; j++) {
        const long gn = n0 + cn + j * 16;
#pragma unroll
        for (int r = 0; r < 4; r++)
          vz[(m0 + cm + i * 16 + r) * 4096 + gn] = f2bf(acc[i][j][r]);
      }
  }

  // k: retile through LDS -> coalesced 256B stores of k[s][i]
  short* scratch = smem;  // 64 rows x 136 shorts = 8704 <= 12288
#pragma unroll
  for (int h = 0; h < 2; h++) {
    __syncthreads();
    if (role == 0 && wn == h) {
#pragma unroll
      for (int j = 0; j < 4; j++)
#pragma unroll
        for (int i = 0; i < 4; i++) {
          const int nloc = j * 16 + l16;
          const int m = wm * 64 + i * 16 + quad * 4;
          short4v pk;
#pragma unroll
          for (int r = 0; r < 4; r++) pk[r] = f2bf(acc[i][j][r]);
          *(short4v*)&scratch[nloc * 136 + m] = pk;
        }
    }
    __syncthreads();
    {
      // drain full 64 x 128 tile: 512 threads x 16 shorts
      const int row = tid >> 3;        // 0..63
      const int off = (tid & 7) * 16;  // 0..112
      short8 v0 = *(const short8*)&scratch[row * 136 + off];
      short8 v1 = *(const short8*)&scratch[row * 136 + off + 8];
      *(short8*)&kz[(n0 + h * 64 + row) * 512 + m0 + off] = v0;
      *(short8*)&kz[(n0 + h * 64 + row) * 512 + m0 + off + 8] = v1;
    }
  }
}

// ---------------- vis fp32 (b,c,s) -> visT bf16 (b,s,c) ----------------
__global__ __launch_bounds__(256) void transpose_f2b(
    const float* __restrict__ vis, short* __restrict__ visT) {
  __shared__ alignas(16) short buf[64][68];
  const int tid = threadIdx.x;
  const long bz = blockIdx.z;
  const long s0 = (long)blockIdx.x * 64;
  const long c0 = (long)blockIdx.y * 64;
  const float* src = vis + bz * 512 * 4096;
  short* dst = visT + bz * 4096 * 512;
  const int tr = tid >> 4;
  const int tc4 = (tid & 15) * 4;
#pragma unroll
  for (int i = 0; i < 4; i++) {
    const int c = tr + i * 16;
    float4v val = *(const float4v*)&src[(c0 + c) * 4096 + s0 + tc4];
    buf[tc4 + 0][c] = f2bf(val[0]);
    buf[tc4 + 1][c] = f2bf(val[1]);
    buf[tc4 + 2][c] = f2bf(val[2]);
    buf[tc4 + 3][c] = f2bf(val[3]);
  }
  __syncthreads();
#pragma unroll
  for (int i = 0; i < 4; i++) {
    const int s = tr + i * 16;
    short4v val = *(const short4v*)&buf[s][tc4];
    *(short4v*)&dst[(s0 + s) * 512 + c0 + tc4] = val;
  }
}

// ---------------- attention partial: block = (head, batch, s-chunk) ----------------
// Each block covers 4096/NCH s-positions; no-max softmax partials.
// XOR-swizzled LDS; k/v fragment reads hoisted to registers so next chunk's
// staging overlaps QK -> softmax -> PV.
__global__ __launch_bounds__(256) void attn_part(
    const short* __restrict__ q, const short* __restrict__ kws,
    const short* __restrict__ vws, float* __restrict__ Opart,
    float* __restrict__ lpart, int b0) {
  const int h = blockIdx.x;
  const int bz = blockIdx.y;
  const int ch = blockIdx.z;
  const int tid = threadIdx.x;
  const int lane = tid & 63, w = tid >> 6;
  const int quad = lane >> 4, l16 = lane & 15;

  __shared__ alignas(16) short lq[64 * 64];
  __shared__ alignas(16) short lk[128 * 64];
  __shared__ alignas(16) short lv[64 * 128];
  __shared__ alignas(16) short lp[64 * 128];
  __shared__ float lsum[64];

  const short* qb = q + ((long)(b0 + bz) * 64) * 512 + h * 64;
  const short* kb = kws + (long)bz * 4096 * 512 + h * 64;
  const short* vb = vws + (long)bz * 512 * 4096 + (long)h * 64 * 4096;

  if (tid < 64) lsum[tid] = 0.0f;
  {
    // lq: 64 rows x 8 chunks; slot (r, c) <- global chunk c ^ (r&7)
    const int qr = tid >> 3;
    const int qc = ((tid & 7) ^ (qr & 7)) * 8;
    load_lds16(&qb[qr * 512 + qc], &lq[tid * 8]);
    load_lds16(&qb[(32 + qr) * 512 + qc], &lq[2048 + tid * 8]);  // (32+qr)&7 == qr&7
  }
  // prologue: stage first k/v chunk (overlaps q fragment setup)
  const int s0_first = ch * (4096 / NCH);
  const int send = s0_first + (4096 / NCH);
#pragma unroll
  for (int it = 0; it < 4; it++) {
    const int li = tid + it * 256;
    const int kr = li >> 3;
    const int kc = ((li & 7) ^ (kr & 7)) * 8;
    load_lds16(&kb[(long)(s0_first + kr) * 512 + kc], &lk[li * 8]);
  }
#pragma unroll
  for (int it = 0; it < 4; it++) {
    const int li = tid + it * 256;
    const int vr = li >> 4;
    const int vc = ((li & 15) ^ (vr & 7)) * 8;
    load_lds16(&vb[(long)vr * 4096 + s0_first + vc], &lv[li * 8]);
  }
  __syncthreads();  // lq + first k/v landed

  short8 aq[4][2];
#pragma unroll
  for (int mt = 0; mt < 4; mt++)
#pragma unroll
    for (int ks = 0; ks < 2; ks++) {
      const int ra = mt * 16 + l16;
      aq[mt][ks] = *(const short8*)&lq[ra * 64 + (((ks * 4 + quad) ^ (ra & 7)) * 8)];
    }

  float4v osc[4];
#pragma unroll
  for (int mt = 0; mt < 4; mt++) osc[mt] = (float4v)0.0f;
  float lrow[4][4] = {};

  for (int s0 = s0_first; s0 < send; s0 += 128) {
    // pull ALL lk/lv fragments for this chunk into regs
    short8 bk[2][2];  // [ks][jn]
#pragma unroll
    for (int ks = 0; ks < 2; ks++)
#pragma unroll
      for (int jn = 0; jn < 2; jn++) {
        const int rb = (2 * w + jn) * 16 + l16;
        bk[ks][jn] = *(const short8*)&lk[rb * 64 + (((ks * 4 + quad) ^ (rb & 7)) * 8)];
      }
    short8 bv[4];
#pragma unroll
    for (int ks = 0; ks < 4; ks++) {
      const int rv = w * 16 + l16;
      bv[ks] = *(const short8*)&lv[rv * 128 + (((ks * 4 + quad) ^ (rv & 7)) * 8)];
    }
    __syncthreads();  // all waves done with lk/lv

    if (s0 + 128 < send) {  // stage next chunk; overlaps QK+softmax+PV
#pragma unroll
      for (int it = 0; it < 4; it++) {
        const int li = tid + it * 256;
        const int kr = li >> 3;
        const int kc = ((li & 7) ^ (kr & 7)) * 8;
        load_lds16(&kb[(long)(s0 + 128 + kr) * 512 + kc], &lk[li * 8]);
      }
#pragma unroll
      for (int it = 0; it < 4; it++) {
        const int li = tid + it * 256;
        const int vr = li >> 4;
        const int vc = ((li & 15) ^ (vr & 7)) * 8;
        load_lds16(&vb[(long)vr * 4096 + s0 + 128 + vc], &lv[li * 8]);
      }
    }

    // scores: wave w covers s-tiles {2w, 2w+1}
    float4v sc[4][2];
#pragma unroll
    for (int mt = 0; mt < 4; mt++)
#pragma unroll
      for (int jn = 0; jn < 2; jn++) sc[mt][jn] = (float4v)0.0f;
#pragma unroll
    for (int ks = 0; ks < 2; ks++)
#pragma unroll
      for (int mt = 0; mt < 4; mt++)
#pragma unroll
        for (int jn = 0; jn < 2; jn++)
          sc[mt][jn] = mfma16x16x32(aq[mt][ks], bk[ks][jn], sc[mt][jn]);

    // p = exp(clamped score); bf16-quantized row sums; park p in lp (row-XOR).
#pragma unroll
    for (int mt = 0; mt < 4; mt++)
#pragma unroll
      for (int jn = 0; jn < 2; jn++)
#pragma unroll
        for (int r = 0; r < 4; r++) {
          const float scv = fminf(fmaxf(sc[mt][jn][r], -80.0f), 30.0f);
          const short sp = f2bf(__expf(scv));
          lrow[mt][r] += bf2f(sp);
          const int rowp = mt * 16 + quad * 4 + r;
          const int col = (2 * w + jn) * 16 + l16;
          lp[rowp * 128 + (((col >> 3) ^ (rowp & 7)) * 8) + (col & 7)] = sp;
        }
    __syncthreads();  // lp ready (next k/v staging still in flight — fine)

    // PV from lp (this-iter data) and bv regs
#pragma unroll
    for (int ks = 0; ks < 4; ks++)
#pragma unroll
      for (int mt = 0; mt < 4; mt++) {
        const int rp = mt * 16 + l16;
        const short8 ap = *(const short8*)&lp[rp * 128 + (((ks * 4 + quad) ^ (rp & 7)) * 8)];
        osc[mt] = mfma16x16x32(ap, bv[ks], osc[mt]);
      }
    __syncthreads();  // everyone done with lp; next-iter frag reads follow
  }

#pragma unroll
  for (int mt = 0; mt < 4; mt++)
#pragma unroll
    for (int r = 0; r < 4; r++) {
      float v = lrow[mt][r];
      v += __shfl_xor(v, 1);
      v += __shfl_xor(v, 2);
      v += __shfl_xor(v, 4);
      v += __shfl_xor(v, 8);
      if (l16 == 0) atomicAdd(&lsum[mt * 16 + quad * 4 + r], v);
    }
  __syncthreads();

  const long bh = bz * 8 + h;
  float* op = Opart + ((bh * NCH + ch) * 64) * 64 + w * 16 + l16;
#pragma unroll
  for (int mt = 0; mt < 4; mt++)
#pragma unroll
    for (int r = 0; r < 4; r++)
      op[(long)(mt * 16 + quad * 4 + r) * 64] = osc[mt][r];
  if (tid < 64) lpart[(bh * NCH + ch) * 64 + tid] = lsum[tid];
}

// ---------------- combine attention partials -> tmp bf16 (b,t,i) ----------------
__global__ __launch_bounds__(256) void attn_combine(
    const float* __restrict__ Opart, const float* __restrict__ lpart,
    short* __restrict__ tmp, int b0, int nbh) {
  const int total = nbh * 4096;
  for (int idx = blockIdx.x * 256 + threadIdx.x; idx < total;
       idx += gridDim.x * 256) {
    const int bh = idx >> 12;
    const int td = idx & 4095;
    const int t = td >> 6, d = td & 63;
    float o = 0.0f, l = 0.0f;
#pragma unroll
    for (int c = 0; c < NCH; c++) {
      o += Opart[((long)bh * NCH + c) * 4096 + td];
      l += lpart[(bh * NCH + c) * 64 + t];
    }
    const int b = b0 + (bh >> 3), h = bh & 7;
    tmp[((long)b * 64 + t) * 512 + h * 64 + d] = f2bf(o / l);
  }
}

// ---------------- launch ----------------
extern "C" void kernel_launch(void* const* d_in, const int* in_sizes, int n_in,
                              void* d_out, int out_size, void* d_ws, size_t ws_size,
                              hipStream_t stream) {
  (void)in_sizes; (void)n_in; (void)out_size;
  const float* vis = (const float*)d_in[0];   // [16][512][4096] fp32
  const float* lang = (const float*)d_in[1];  // [16][64][512]  fp32
  const float* Wq = (const float*)d_in[3];    // [512][512] fp32
  const float* Wk = (const float*)d_in[4];
  const float* Wv = (const float*)d_in[5];
  const float* Wo = (const float*)d_in[6];
  float* out = (float*)d_out;                 // [16][64][512] fp32

  char* ws = (char*)d_ws;
  const size_t MB = 1 << 20;
  short* q_ws = (short*)(ws + 0 * MB);
  short* tmp_ws = (short*)(ws + 1 * MB);
  short* langb = (short*)(ws + 2 * MB);
  short* Wqb = (short*)(ws + 3 * MB);
  short* Wkb = (short*)(ws + 3 * MB + 512 * 1024);
  short* Wvb = (short*)(ws + 4 * MB);
  short* Wob = (short*)(ws + 4 * MB + 512 * 1024);
  char* grp = ws + 5 * MB;

  const long batch_elems = 4096l * 512;
  int g = 16;
  const int cands[5] = {1, 2, 4, 8, 16};
  for (int ci = 0; ci < 5; ci++) {
    const size_t need = 5 * MB + 3ull * (16 / cands[ci]) * batch_elems * 2;
    if (need <= ws_size) { g = cands[ci]; break; }
  }
  const int Bg = 16 / g;
  short* visT = (short*)grp;                    // [Bg][4096][512]
  short* k_ws = visT + (long)Bg * batch_elems;  // [Bg][4096][512] (s,i)
  short* v_ws = k_ws + (long)Bg * batch_elems;  // [Bg][512][4096] (i,s)
  // attn partials alias visT (dead by attn time)
  float* Opart = (float*)visT;
  float* lptr = Opart + (long)Bg * 8 * NCH * 4096;

  convert5<<<dim3(128, 5), 256, 0, stream>>>(lang, langb, Wq, Wqb, Wk, Wkb,
                                             Wv, Wvb, Wo, Wob);

  // q = SCALE * lang @ Wq^T
  gemm_nt<0><<<dim3(4, 8), 256, 0, stream>>>(langb, Wqb, q_ws, 512, 512, 0.125f);

  for (int gi = 0; gi < g; gi++) {
    const int b0 = gi * Bg;
    transpose_f2b<<<dim3(64, 8, Bg), 256, 0, stream>>>(vis + (long)b0 * batch_elems, visT);
    gemm_kv<<<dim3(32, 4, Bg), 512, 0, stream>>>(Wkb, Wvb, visT, batch_elems,
                                                 k_ws, v_ws, batch_elems);
    attn_part<<<dim3(8, Bg, NCH), 256, 0, stream>>>(q_ws, k_ws, v_ws, Opart, lptr, b0);
    attn_combine<<<512, 256, 0, stream>>>(Opart, lptr, tmp_ws, b0, Bg * 8);
  }

  // out = tmp @ Wo^T, fp32 epilogue
  gemm_nt<1><<<dim3(4, 8), 256, 0, stream>>>(tmp_ws, Wob, out, 512, 512, 1.0f);
}